// Round 5
// baseline (225.440 us; speedup 1.0000x reference)
//
#include <hip/hip_runtime.h>

// GroupConv2D: NHWC, B=32, H=W=56, Cin=Cout=256, groups=8 (32 ch/group), 3x3 SAME.
// Implicit-GEMM per group: 16x16 tiles, K=288 (9 taps x 32 ci), mfma_f32_16x16x32_bf16.
//
// R7 = R6 resubmit (container infra failure, hypothesis unmeasured) + defensive tweaks.
// Evidence: R1/R2/R3/R5 all pin at 2.2-2.3 TB/s regardless of occupancy (35->63% did
// nothing); time tracks staging-instruction count. Invariant: staging goes through
// registers because of fp32->bf16 convert (load -> vmcnt -> f2bf -> ds_write); the
// scheduler never holds >1 load in flight (R3), register pipelining spills (R4).
//  FIX: remove the conversion from the staging path entirely.
//   - iprep: streaming fp32->bf16 pre-pass into d_ws (51.4 MB, NHWC bf16).
//   - gconv_bf16: halo staged via __builtin_amdgcn_global_load_lds width=16 --
//     fire-and-forget DMA, ~6 instrs/wave, nothing to re-serialize, no spillable
//     state. OOB lanes read a zeroed 64B pad in ws (per-lane global src legal;
//     LDS dest wave-uniform linear). Compute/epilogue identical to R5 (passed).
// Predict: iprep ~25-31 us @ ~5-6 TB/s; gconv 78 -> ~25-35 us (FETCH ~30-55 MB,
// WRITE ~100 MB). If gconv stays >=60 us, staging was never the wall -> ablate.

#define R_ 4                 // output rows per block

typedef __bf16 bf16x8 __attribute__((ext_vector_type(8)));
typedef float floatx4 __attribute__((ext_vector_type(4)));
typedef unsigned short ushortx4 __attribute__((ext_vector_type(4)));
typedef unsigned short ushortx8 __attribute__((ext_vector_type(8)));

#define IMG_USHORTS 25690112u   // 32*56*56*256 bf16 elements in ws
#define WGT_USHORTS 73728u      // 8*9*32*32
#define ZPAD_USHORTS 64u

__device__ __forceinline__ unsigned short f2bf(float f) {
    unsigned int u = __builtin_bit_cast(unsigned int, f);
    u += 0x7fffu + ((u >> 16) & 1u);           // round-to-nearest-even
    return (unsigned short)(u >> 16);
}

// ---- iprep: fp32 NHWC -> bf16 NHWC, pure streaming (8 elems/thread/iter)
__global__ __launch_bounds__(256)
void iprep(const float* __restrict__ in, unsigned short* __restrict__ obf) {
    const int n8 = 3211264;                    // 25.69M / 8
    const int stride = gridDim.x * 256;
    for (int i = blockIdx.x * 256 + threadIdx.x; i < n8; i += stride) {
        const float4 a = *reinterpret_cast<const float4*>(&in[i * 8]);
        const float4 b = *reinterpret_cast<const float4*>(&in[i * 8 + 4]);
        ushortx8 p;
        p[0] = f2bf(a.x); p[1] = f2bf(a.y); p[2] = f2bf(a.z); p[3] = f2bf(a.w);
        p[4] = f2bf(b.x); p[5] = f2bf(b.y); p[6] = f2bf(b.z); p[7] = f2bf(b.w);
        *reinterpret_cast<ushortx8*>(&obf[i * 8]) = p;
    }
}

// ---- wprep: wgt fp32 [tap][ci][co256] -> bf16 [g][tap][co][ci]; also zero pad
__global__ __launch_bounds__(256)
void wprep(const float* __restrict__ wgt, unsigned short* __restrict__ wbf) {
    const int i = blockIdx.x * 256 + threadIdx.x;       // grid sized exactly (288 blocks)
    if (blockIdx.x == 0 && threadIdx.x < ZPAD_USHORTS)
        wbf[WGT_USHORTS + threadIdx.x] = 0;             // zero pad after weights
    const int co256 = i & 255;
    const int tmp   = i >> 8;
    const int ci    = tmp & 31;
    const int kk    = tmp >> 5;                          // 0..8
    const int g  = co256 >> 5;
    const int co = co256 & 31;
    wbf[((g * 9 + kk) * 32 + co) * 32 + ci] = f2bf(wgt[i]);
}

// ---- main kernel: halo staged by global_load_lds (bf16, no conversion)
__global__ __launch_bounds__(256, 7)
void gconv_bf16(const unsigned short* __restrict__ bfin,
                const unsigned short* __restrict__ wbf,
                const float* __restrict__ bias, float* __restrict__ out) {
    const int rt = blockIdx.x;      // 0..13 row-strip (4 rows each)
    const int g  = blockIdx.y;      // 0..7 group
    const int b  = blockIdx.z;      // 0..31 batch
    const int y0 = rt * R_;

    // [row][col][ci] bf16: 6*58=348 slices of 64B, padded to 352 -> 22528 B
    __shared__ unsigned short lds_in[352 * 32];

    const int tid  = threadIdx.x;
    const int wv   = tid >> 6;
    const int lane = tid & 63;
    const unsigned short* zpad = wbf + WGT_USHORTS;

    // ---- stage halo: 22 wave-instructions of 1KB (16 slices each), round-robin
    // over waves (6/6/5/5). LDS dest = wave-uniform base + lane*16 (linear).
    // Per-lane global src; OOB lanes -> zero pad. Slice s dest ushort offset
    // = s*32 + (lane&3)*8, matching compute-side (row*58+col)*32 addressing.
    for (int i = wv; i < 22; i += 4) {
        const int s   = (i << 4) + (lane >> 2);        // slice 0..351
        const int row = s / 58;
        const int col = s - row * 58;
        const unsigned gy = (unsigned)(y0 - 1 + row);
        const unsigned gx = (unsigned)(col - 1);
        const bool ok = (s < 348) & (gy < 56u) & (gx < 56u);
        const unsigned short* src = ok
            ? &bfin[(((b * 56 + (int)gy) * 56 + (int)gx) << 8) + (g << 5) + ((lane & 3) << 3)]
            : zpad;
        __builtin_amdgcn_global_load_lds(
            (const __attribute__((address_space(1))) void*)src,
            (__attribute__((address_space(3))) void*)&lds_in[i << 9],   // i*1024 B
            16, 0, 0);
    }

    __syncthreads();   // compiler drains vmcnt here -> staging complete

    const int lc   = lane & 15;    // weights-A: m (co); pixels-B: n (pixel)
    const int quad = lane >> 4;

    // 14 pixel tiles (224 px / 16); waves 0,1: 4 tiles; waves 2,3: 3 tiles
    const int nt = (wv < 2) ? 4 : 3;
    const int t0 = (wv < 2) ? (wv * 4) : (8 + (wv - 2) * 3);

    int lane_base[4];
#pragma unroll
    for (int t = 0; t < 4; ++t) {
        const int tt = (t < nt) ? (t0 + t) : 0;
        const int p  = tt * 16 + lc;           // output pixel 0..223 in strip
        const int yl = p / 56;
        lane_base[t] = (yl * 58 + (p - yl * 56)) * 32 + (quad << 3);
    }

    // weight fragment base: [g][kk][co][ci] bf16; lane (lc,quad) -> co=lc, ci=quad*8
    const unsigned short* wq = &wbf[(g * 9 * 32) * 32 + (quad << 3)];

    floatx4 acc[4][2];
#pragma unroll
    for (int t = 0; t < 4; ++t) { acc[t][0] = (floatx4)(0.f); acc[t][1] = (floatx4)(0.f); }

    bf16x8 b0 = *reinterpret_cast<const bf16x8*>(&wq[(0 * 32 + lc) * 32]);
    bf16x8 b1 = *reinterpret_cast<const bf16x8*>(&wq[(0 * 32 + 16 + lc) * 32]);

#pragma unroll
    for (int kk = 0; kk < 9; ++kk) {
        const int koff = ((kk / 3) * 58 + (kk % 3)) * 32;   // wave-uniform tap offset
        bf16x8 nb0 = b0, nb1 = b1;
        if (kk < 8) {   // prefetch next tap while MFMAs run (L2-hot)
            nb0 = *reinterpret_cast<const bf16x8*>(&wq[((kk + 1) * 32 + lc) * 32]);
            nb1 = *reinterpret_cast<const bf16x8*>(&wq[((kk + 1) * 32 + 16 + lc) * 32]);
        }
#pragma unroll
        for (int t = 0; t < 4; ++t) {
            if (t < nt) {   // wave-uniform guard
                const bf16x8 a = *reinterpret_cast<const bf16x8*>(
                    &lds_in[lane_base[t] + koff]);
                // A=weights (m=co), B=pixels (n=pixel) -> D[row=co][col=pixel]
                acc[t][0] = __builtin_amdgcn_mfma_f32_16x16x32_bf16(b0, a, acc[t][0], 0, 0, 0);
                acc[t][1] = __builtin_amdgcn_mfma_f32_16x16x32_bf16(b1, a, acc[t][1], 0, 0, 0);
            }
        }
        b0 = nb0; b1 = nb1;
    }

    // ---- epilogue: D row=quad*4+r (co), col=lc (pixel); two dwordx4 per tile.
    const float4 bv0 = *reinterpret_cast<const float4*>(&bias[(g << 5) + (quad << 2)]);
    const float4 bv1 = *reinterpret_cast<const float4*>(&bias[(g << 5) + 16 + (quad << 2)]);
    const int obase = (((b * 56 + y0) * 56) << 8) + (g << 5) + (quad << 2);
#pragma unroll
    for (int t = 0; t < 4; ++t) {
        if (t < nt) {
            const int p = (t0 + t) * 16 + lc;
            const int y = p / 56;
            const int x = p - y * 56;
            float* o = &out[obase + ((y * 56 + x) << 8)];
            float4 s0, s1;
            s0.x = acc[t][0][0] + bv0.x; s0.y = acc[t][0][1] + bv0.y;
            s0.z = acc[t][0][2] + bv0.z; s0.w = acc[t][0][3] + bv0.w;
            s1.x = acc[t][1][0] + bv1.x; s1.y = acc[t][1][1] + bv1.y;
            s1.z = acc[t][1][2] + bv1.z; s1.w = acc[t][1][3] + bv1.w;
            *reinterpret_cast<float4*>(o)      = s0;
            *reinterpret_cast<float4*>(o + 16) = s1;
        }
    }
}

// ---- mid fallback (R5 path, measured 78us): fp32 register staging ----
__global__ __launch_bounds__(256, 7)
void gconv_f32s(const float* __restrict__ in, const unsigned short* __restrict__ wbf,
                const float* __restrict__ bias, float* __restrict__ out) {
    const int rt = blockIdx.x, g = blockIdx.y, b = blockIdx.z;
    const int y0 = rt * R_;
    __shared__ unsigned short lds_in[6 * 58 * 32];
    const int tid = threadIdx.x;
#pragma unroll
    for (int i = 0; i < 11; ++i) {
        const int c = tid + (i << 8);
        if (c < 6 * 58 * 8) {
            const int row = c / 464, rem = c - row * 464, col = rem >> 3, q = rem & 7;
            const int gy = y0 - 1 + row, gx = col - 1;
            float4 v = make_float4(0.f, 0.f, 0.f, 0.f);
            if ((unsigned)gy < 56u && (unsigned)gx < 56u)
                v = *reinterpret_cast<const float4*>(
                    &in[((((b * 56 + gy) * 56 + gx)) << 8) + (g << 5) + (q << 2)]);
            ushortx4 p;
            p.x = f2bf(v.x); p.y = f2bf(v.y); p.z = f2bf(v.z); p.w = f2bf(v.w);
            *reinterpret_cast<ushortx4*>(&lds_in[(row * 58 + col) * 32 + (q << 2)]) = p;
        }
    }
    __syncthreads();
    const int wv = tid >> 6, lane = tid & 63, lc = lane & 15, quad = lane >> 4;
    const int nt = (wv < 2) ? 4 : 3;
    const int t0 = (wv < 2) ? (wv * 4) : (8 + (wv - 2) * 3);
    int lane_base[4];
#pragma unroll
    for (int t = 0; t < 4; ++t) {
        const int tt = (t < nt) ? (t0 + t) : 0;
        const int p = tt * 16 + lc;
        const int yl = p / 56;
        lane_base[t] = (yl * 58 + (p - yl * 56)) * 32 + (quad << 3);
    }
    const unsigned short* wq = &wbf[(g * 9 * 32) * 32 + (quad << 3)];
    floatx4 acc[4][2];
#pragma unroll
    for (int t = 0; t < 4; ++t) { acc[t][0] = (floatx4)(0.f); acc[t][1] = (floatx4)(0.f); }
    bf16x8 b0 = *reinterpret_cast<const bf16x8*>(&wq[(0 * 32 + lc) * 32]);
    bf16x8 b1 = *reinterpret_cast<const bf16x8*>(&wq[(0 * 32 + 16 + lc) * 32]);
#pragma unroll
    for (int kk = 0; kk < 9; ++kk) {
        const int koff = ((kk / 3) * 58 + (kk % 3)) * 32;
        bf16x8 nb0 = b0, nb1 = b1;
        if (kk < 8) {
            nb0 = *reinterpret_cast<const bf16x8*>(&wq[((kk + 1) * 32 + lc) * 32]);
            nb1 = *reinterpret_cast<const bf16x8*>(&wq[((kk + 1) * 32 + 16 + lc) * 32]);
        }
#pragma unroll
        for (int t = 0; t < 4; ++t) {
            if (t < nt) {
                const bf16x8 a = *reinterpret_cast<const bf16x8*>(&lds_in[lane_base[t] + koff]);
                acc[t][0] = __builtin_amdgcn_mfma_f32_16x16x32_bf16(b0, a, acc[t][0], 0, 0, 0);
                acc[t][1] = __builtin_amdgcn_mfma_f32_16x16x32_bf16(b1, a, acc[t][1], 0, 0, 0);
            }
        }
        b0 = nb0; b1 = nb1;
    }
    const float4 bv0 = *reinterpret_cast<const float4*>(&bias[(g << 5) + (quad << 2)]);
    const float4 bv1 = *reinterpret_cast<const float4*>(&bias[(g << 5) + 16 + (quad << 2)]);
    const int obase = (((b * 56 + y0) * 56) << 8) + (g << 5) + (quad << 2);
#pragma unroll
    for (int t = 0; t < 4; ++t) {
        if (t < nt) {
            const int p = (t0 + t) * 16 + lc;
            const int y = p / 56, x = p - y * 56;
            float* o = &out[obase + ((y * 56 + x) << 8)];
            float4 s0, s1;
            s0.x = acc[t][0][0] + bv0.x; s0.y = acc[t][0][1] + bv0.y;
            s0.z = acc[t][0][2] + bv0.z; s0.w = acc[t][0][3] + bv0.w;
            s1.x = acc[t][1][0] + bv1.x; s1.y = acc[t][1][1] + bv1.y;
            s1.z = acc[t][1][2] + bv1.z; s1.w = acc[t][1][3] + bv1.w;
            *reinterpret_cast<float4*>(o)      = s0;
            *reinterpret_cast<float4*>(o + 16) = s1;
        }
    }
}

// ---- last-resort fallback (round-1 kernel, no workspace) ----
__global__ __launch_bounds__(256, 2)
void gconv_mfma_ldsw(const float* __restrict__ in, const float* __restrict__ wgt,
                     const float* __restrict__ bias, float* __restrict__ out) {
    const int rt = blockIdx.x, g = blockIdx.y, b = blockIdx.z;
    const int y0 = rt * 8;
    __shared__ unsigned short lds_in[10 * 58 * 32];
    __shared__ unsigned short lds_w[9 * 32 * 32];
    const int tid = threadIdx.x;
    for (int i = tid; i < 9 * 32 * 32; i += 256) {
        const int co = i & 31, ci = (i >> 5) & 31, kk = i >> 10;
        lds_w[(kk * 32 + co) * 32 + ci] = f2bf(wgt[(kk * 32 + ci) * 256 + g * 32 + co]);
    }
    for (int c = tid; c < 10 * 58 * 8; c += 256) {
        const int row = c / 464, rem = c - row * 464, col = rem >> 3, q = rem & 7;
        const int gy = y0 - 1 + row, gx = col - 1;
        float4 v = make_float4(0.f, 0.f, 0.f, 0.f);
        if ((unsigned)gy < 56u && (unsigned)gx < 56u)
            v = *reinterpret_cast<const float4*>(&in[(((b * 56 + gy) * 56 + gx) * 256) + g * 32 + q * 4]);
        ushortx4 p;
        p.x = f2bf(v.x); p.y = f2bf(v.y); p.z = f2bf(v.z); p.w = f2bf(v.w);
        *reinterpret_cast<ushortx4*>(&lds_in[(row * 58 + col) * 32 + q * 4]) = p;
    }
    __syncthreads();
    const int wv = tid >> 6, lane = tid & 63, lc = lane & 15, quad = lane >> 4;
    int lane_base[7];
#pragma unroll
    for (int t = 0; t < 7; ++t) {
        const int p = (wv * 7 + t) * 16 + lc;
        const int yl = p / 56, xl = p - yl * 56;
        lane_base[t] = (yl * 58 + xl) * 32 + quad * 8;
    }
    floatx4 acc[7][2];
#pragma unroll
    for (int t = 0; t < 7; ++t) { acc[t][0] = (floatx4)(0.f); acc[t][1] = (floatx4)(0.f); }
#pragma unroll
    for (int kk = 0; kk < 9; ++kk) {
        const int ky = kk / 3, kx = kk % 3;
        const int koff = (ky * 58 + kx) * 32;
        const bf16x8 bf0 = *reinterpret_cast<const bf16x8*>(&lds_w[(kk * 32 + lc) * 32 + quad * 8]);
        const bf16x8 bf1 = *reinterpret_cast<const bf16x8*>(&lds_w[(kk * 32 + 16 + lc) * 32 + quad * 8]);
#pragma unroll
        for (int t = 0; t < 7; ++t) {
            const bf16x8 a = *reinterpret_cast<const bf16x8*>(&lds_in[lane_base[t] + koff]);
            acc[t][0] = __builtin_amdgcn_mfma_f32_16x16x32_bf16(a, bf0, acc[t][0], 0, 0, 0);
            acc[t][1] = __builtin_amdgcn_mfma_f32_16x16x32_bf16(a, bf1, acc[t][1], 0, 0, 0);
        }
    }
    const float bv0 = bias[g * 32 + lc], bv1 = bias[g * 32 + 16 + lc];
#pragma unroll
    for (int t = 0; t < 7; ++t)
#pragma unroll
        for (int r = 0; r < 4; ++r) {
            const int p = (wv * 7 + t) * 16 + quad * 4 + r;
            const int y = p / 56, x = p - y * 56;
            float* o = &out[(((b * 56) + y0 + y) * 56 + x) * 256 + g * 32];
            o[lc] = acc[t][0][r] + bv0;
            o[16 + lc] = acc[t][1][r] + bv1;
        }
}

extern "C" void kernel_launch(void* const* d_in, const int* in_sizes, int n_in,
                              void* d_out, int out_size, void* d_ws, size_t ws_size,
                              hipStream_t stream) {
    const float* in   = (const float*)d_in[0];
    const float* wgt  = (const float*)d_in[1];
    const float* bias = (const float*)d_in[2];
    float* out        = (float*)d_out;

    const size_t need_full = (size_t)(IMG_USHORTS + WGT_USHORTS + ZPAD_USHORTS) * 2;
    const size_t need_wgt  = (size_t)WGT_USHORTS * 2;

    if (d_ws != nullptr && ws_size >= need_full) {
        unsigned short* bfin = (unsigned short*)d_ws;
        unsigned short* wbf  = bfin + IMG_USHORTS;
        iprep<<<dim3(2048, 1, 1), dim3(256, 1, 1), 0, stream>>>(in, bfin);
        wprep<<<dim3(288, 1, 1), dim3(256, 1, 1), 0, stream>>>(wgt, wbf);
        gconv_bf16<<<dim3(14, 8, 32), dim3(256, 1, 1), 0, stream>>>(bfin, wbf, bias, out);
    } else if (d_ws != nullptr && ws_size >= need_wgt) {
        unsigned short* wbf = (unsigned short*)d_ws;
        wprep<<<dim3(288, 1, 1), dim3(256, 1, 1), 0, stream>>>(wgt, wbf);
        gconv_f32s<<<dim3(14, 8, 32), dim3(256, 1, 1), 0, stream>>>(in, wbf, bias, out);
    } else {
        gconv_mfma_ldsw<<<dim3(7, 8, 32), dim3(256, 1, 1), 0, stream>>>(in, wgt, bias, out);
    }
}